// Round 1
// baseline (194.952 us; speedup 1.0000x reference)
//
#include <hip/hip_runtime.h>
#include <hip/hip_bf16.h>

#define B_ROWS 4096
#define D_DIM  512
#define N_ROWS 8192
#define INV_T  20.0f
#define EPS_N  1e-8f
#define CSPLIT 2
#define BM 64
#define BN 64
#define COLS_PER_CHUNK (N_ROWS / CSPLIT)       // 4096
#define TILES_PER_BLOCK (COLS_PER_CHUNK / BN)  // 64

typedef __attribute__((ext_vector_type(8))) short short8;
typedef __attribute__((ext_vector_type(4))) float floatx4;

// swizzled LDS fragment load: row-major [64][512] bf16, byte ^= (row&7)<<4
__device__ __forceinline__ short8 ldsFrag(const char* base, int row, int kbyte) {
  int off = (row * 1024 + kbyte) ^ ((row & 7) << 4);
  return *(const short8*)(base + off);
}

// -------------------- kernel 1: normalize -> bf16, dot(f1,f2) --------------------
__global__ __launch_bounds__(256) void prep_kernel(
    const float* __restrict__ f1, const float* __restrict__ f2,
    __hip_bfloat16* __restrict__ fnb, float* __restrict__ dots)
{
  int row = blockIdx.x;          // 0..4095
  int t = threadIdx.x;           // 256 threads, 2 elems each
  const float* r1 = f1 + (size_t)row * D_DIM;
  const float* r2 = f2 + (size_t)row * D_DIM;
  float2 a = *(const float2*)(r1 + 2 * t);
  float2 b = *(const float2*)(r2 + 2 * t);
  float s1 = a.x * a.x + a.y * a.y;
  float s2 = b.x * b.x + b.y * b.y;
  float d  = a.x * b.x + a.y * b.y;
  #pragma unroll
  for (int off = 32; off >= 1; off >>= 1) {
    s1 += __shfl_down(s1, off);
    s2 += __shfl_down(s2, off);
    d  += __shfl_down(d, off);
  }
  __shared__ float red[4][3];
  __shared__ float bc[2];
  int wave = t >> 6, lane = t & 63;
  if (lane == 0) { red[wave][0] = s1; red[wave][1] = s2; red[wave][2] = d; }
  __syncthreads();
  if (t == 0) {
    float S1 = red[0][0] + red[1][0] + red[2][0] + red[3][0];
    float S2 = red[0][1] + red[1][1] + red[2][1] + red[3][1];
    float Dd = red[0][2] + red[1][2] + red[2][2] + red[3][2];
    bc[0] = 1.0f / fmaxf(sqrtf(S1), EPS_N);
    bc[1] = 1.0f / fmaxf(sqrtf(S2), EPS_N);
    dots[row] = Dd;
  }
  __syncthreads();
  float sc1 = bc[0], sc2 = bc[1];
  __hip_bfloat16* o1 = fnb + (size_t)row * D_DIM;
  __hip_bfloat16* o2 = fnb + (size_t)(row + B_ROWS) * D_DIM;
  o1[2 * t]     = __float2bfloat16(a.x * sc1);
  o1[2 * t + 1] = __float2bfloat16(a.y * sc1);
  o2[2 * t]     = __float2bfloat16(b.x * sc2);
  o2[2 * t + 1] = __float2bfloat16(b.y * sc2);
}

// ---- kernel 2: fused sim tile (MFMA) + exp-sum + top-5 per row, per chunk ----
__global__ __launch_bounds__(256, 1) void sim_kernel(
    const __hip_bfloat16* __restrict__ fnb,
    float* __restrict__ partials)      // [N_ROWS][CSPLIT][6] = sum, top5 (desc)
{
  __shared__ int4 lds4[8192];          // 128 KiB
  char* As = (char*)lds4;              // 64 KiB: A panel 64x512 bf16 (swizzled)
  char* Bs = As + 65536;               // 64 KiB: B tile  64x512 bf16 (swizzled)
  float* Cs = (float*)Bs;              // reused for C tile, stride 68 floats

  int bx = blockIdx.x;                 // 0..255
  int rowtile = bx >> 1;
  int chunk = bx & 1;
  int rowbase = rowtile * BM;
  int colchunkbase = chunk * COLS_PER_CHUNK;

  int t = threadIdx.x;
  int wave = t >> 6, lane = t & 63;
  int wr = wave >> 1, wc = wave & 1;   // 2x2 wave grid, 32x32 per wave

  // ---- stage A panel once (reg-staged, swizzled write) ----
  {
    const char* gsrc = (const char*)(fnb + (size_t)rowbase * D_DIM);
    #pragma unroll
    for (int i = 0; i < 16; ++i) {
      int c = i * 256 + t;             // 4096 x 16B chunks
      int row = c >> 6;
      int kc = c & 63;
      int4 v = *(const int4*)(gsrc + (size_t)row * 1024 + kc * 16);
      int dst = (row * 1024 + kc * 16) ^ ((row & 7) << 4);
      *(int4*)(As + dst) = v;
    }
  }

  // per-thread scan state: row = t&63, col-group = t>>6 (16 cols each)
  float sum = 0.0f;
  float top[5] = {0.f, 0.f, 0.f, 0.f, 0.f};   // exp-space, sorted desc
  int srow = t & 63;
  int scg = t >> 6;
  int grow = rowbase + srow;

  for (int tile = 0; tile < TILES_PER_BLOCK; ++tile) {
    int colbase = colchunkbase + tile * BN;
    // ---- stage B tile ----
    {
      const char* gsrc = (const char*)(fnb + (size_t)colbase * D_DIM);
      #pragma unroll
      for (int i = 0; i < 16; ++i) {
        int c = i * 256 + t;
        int row = c >> 6;
        int kc = c & 63;
        int4 v = *(const int4*)(gsrc + (size_t)row * 1024 + kc * 16);
        int dst = (row * 1024 + kc * 16) ^ ((row & 7) << 4);
        *(int4*)(Bs + dst) = v;
      }
    }
    __syncthreads();

    floatx4 acc00 = {0.f, 0.f, 0.f, 0.f};
    floatx4 acc01 = {0.f, 0.f, 0.f, 0.f};
    floatx4 acc10 = {0.f, 0.f, 0.f, 0.f};
    floatx4 acc11 = {0.f, 0.f, 0.f, 0.f};
    #pragma unroll
    for (int ks = 0; ks < 16; ++ks) {
      int kb = ks * 64 + ((lane >> 4) << 4);   // byte offset of this lane's k
      int r0 = wr * 32 + (lane & 15);
      int c0 = wc * 32 + (lane & 15);
      short8 a0 = ldsFrag(As, r0,      kb);
      short8 a1 = ldsFrag(As, r0 + 16, kb);
      short8 b0 = ldsFrag(Bs, c0,      kb);
      short8 b1 = ldsFrag(Bs, c0 + 16, kb);
      acc00 = __builtin_amdgcn_mfma_f32_16x16x32_bf16(a0, b0, acc00, 0, 0, 0);
      acc01 = __builtin_amdgcn_mfma_f32_16x16x32_bf16(a0, b1, acc01, 0, 0, 0);
      acc10 = __builtin_amdgcn_mfma_f32_16x16x32_bf16(a1, b0, acc10, 0, 0, 0);
      acc11 = __builtin_amdgcn_mfma_f32_16x16x32_bf16(a1, b1, acc11, 0, 0, 0);
    }
    __syncthreads();   // all waves done reading Bs before C overwrites it

    // ---- spill C tile to LDS (stride 68 floats; C/D layout: col=lane&15, row=(lane>>4)*4+j) ----
    {
      int cr = wr * 32 + ((lane >> 4) << 2);
      int cc = wc * 32 + (lane & 15);
      #pragma unroll
      for (int j = 0; j < 4; ++j) {
        Cs[(cr + j) * 68 + cc]            = acc00[j];
        Cs[(cr + j) * 68 + cc + 16]       = acc01[j];
        Cs[(cr + 16 + j) * 68 + cc]       = acc10[j];
        Cs[(cr + 16 + j) * 68 + cc + 16]  = acc11[j];
      }
    }
    __syncthreads();

    // ---- scan: exp-sum + top-5 (diag excluded) ----
    #pragma unroll
    for (int q = 0; q < 4; ++q) {
      float4 v4 = *(const float4*)(&Cs[srow * 68 + scg * 16 + q * 4]);
      float vv[4] = {v4.x, v4.y, v4.z, v4.w};
      #pragma unroll
      for (int e = 0; e < 4; ++e) {
        int gc = colbase + scg * 16 + q * 4 + e;
        float ev = __expf(vv[e] * INV_T);
        ev = (gc == grow) ? 0.0f : ev;
        sum += ev;
        float b2 = ev;
        #pragma unroll
        for (int i5 = 0; i5 < 5; ++i5) {
          float hi = fmaxf(top[i5], b2);
          float lo = fminf(top[i5], b2);
          top[i5] = hi;
          b2 = lo;
        }
      }
    }
    __syncthreads();   // scan done before next B staging overwrites Cs
  }

  // ---- merge the 4 col-group threads of each row, write partials ----
  float* m = (float*)As;               // 256 x 6 floats (A panel is dead now)
  m[t * 6 + 0] = sum;
  #pragma unroll
  for (int k = 0; k < 5; ++k) m[t * 6 + 1 + k] = top[k];
  __syncthreads();
  if (t < 64) {
    float tsum = 0.0f;
    float a5[5] = {0.f, 0.f, 0.f, 0.f, 0.f};
    #pragma unroll
    for (int p = 0; p < 4; ++p) {
      const float* src = m + (size_t)(p * 64 + t) * 6;
      tsum += src[0];
      #pragma unroll
      for (int k = 0; k < 5; ++k) {
        float b2 = src[1 + k];
        #pragma unroll
        for (int i5 = 0; i5 < 5; ++i5) {
          float hi = fmaxf(a5[i5], b2);
          float lo = fminf(a5[i5], b2);
          a5[i5] = hi;
          b2 = lo;
        }
      }
    }
    float* dst = partials + ((size_t)(rowbase + t) * CSPLIT + chunk) * 6;
    dst[0] = tsum;
    #pragma unroll
    for (int k = 0; k < 5; ++k) dst[1 + k] = a5[k];
  }
}

// -------------------- kernel 3: merge chunks, loss --------------------
__global__ __launch_bounds__(1024) void finalize_kernel(
    const float* __restrict__ partials, const float* __restrict__ dots,
    float* __restrict__ out)
{
  int t = threadIdx.x;
  float acc = 0.0f;
  #pragma unroll
  for (int i = 0; i < N_ROWS / 1024; ++i) {
    int row = i * 1024 + t;
    const float* p = partials + (size_t)row * (CSPLIT * 6);
    float sum = p[0] + p[6];
    float a5[5];
    #pragma unroll
    for (int k = 0; k < 5; ++k) a5[k] = p[1 + k];
    #pragma unroll
    for (int k = 0; k < 5; ++k) {
      float b2 = p[7 + k];
      #pragma unroll
      for (int i5 = 0; i5 < 5; ++i5) {
        float hi = fmaxf(a5[i5], b2);
        float lo = fminf(a5[i5], b2);
        a5[i5] = hi;
        b2 = lo;
      }
    }
    float ng = sum - (a5[0] + a5[1] + a5[2] + a5[3] + a5[4]);
    float dv = dots[row & (B_ROWS - 1)];
    float pv = __expf(dv * INV_T);
    acc += __logf(ng + pv) - dv * INV_T;
  }
  #pragma unroll
  for (int off = 32; off >= 1; off >>= 1) acc += __shfl_down(acc, off);
  __shared__ float red[16];
  int wave = t >> 6, lane = t & 63;
  if (lane == 0) red[wave] = acc;
  __syncthreads();
  if (t == 0) {
    float tot = 0.0f;
    #pragma unroll
    for (int w = 0; w < 16; ++w) tot += red[w];
    out[0] = tot / (float)N_ROWS;
  }
}

extern "C" void kernel_launch(void* const* d_in, const int* in_sizes, int n_in,
                              void* d_out, int out_size, void* d_ws, size_t ws_size,
                              hipStream_t stream) {
  const float* f1 = (const float*)d_in[0];
  const float* f2 = (const float*)d_in[1];
  float* out = (float*)d_out;
  char* ws = (char*)d_ws;

  __hip_bfloat16* fnb = (__hip_bfloat16*)ws;                          // 8 MiB
  float* dots = (float*)(ws + (size_t)8 * 1024 * 1024);               // 16 KiB
  float* partials = (float*)(ws + (size_t)8 * 1024 * 1024 + 65536);   // 384 KiB

  prep_kernel<<<B_ROWS, 256, 0, stream>>>(f1, f2, fnb, dots);
  sim_kernel<<<(N_ROWS / BM) * CSPLIT, 256, 0, stream>>>(fnb, partials);
  finalize_kernel<<<1, 1024, 0, stream>>>(partials, dots, out);
}